// Round 10
// baseline (207.856 us; speedup 1.0000x reference)
//
#include <hip/hip_runtime.h>

#define B_  4
#define S_  1024
#define D_  1024
#define H_  16
#define HD_ 64
#define EPS_ 1e-5f

typedef _Float16 f16x8 __attribute__((ext_vector_type(8)));
typedef _Float16 f16x4 __attribute__((ext_vector_type(4)));
typedef __bf16 bf16x8 __attribute__((ext_vector_type(8)));
typedef float  f32x4  __attribute__((ext_vector_type(4)));
typedef unsigned short ushort8v __attribute__((ext_vector_type(8)));

static __device__ __forceinline__ unsigned short f2bf(float f) {
  union { float f; unsigned u; } v; v.f = f;
  unsigned r = v.u + 0x7fffu + ((v.u >> 16) & 1u);
  return (unsigned short)(r >> 16);
}
static __device__ __forceinline__ float bf2f(unsigned short u) {
  union { unsigned u; float f; } v; v.u = ((unsigned)u) << 16;
  return v.f;
}

// async global->LDS, 16B per lane; LDS dest is wave-uniform base + lane*16
#define GLD16(gp, lp) __builtin_amdgcn_global_load_lds( \
    (const __attribute__((address_space(1))) void*)(gp), \
    (__attribute__((address_space(3))) void*)(lp), 16, 0, 0)

// ---------------------------------------------------------------- convert ---
__global__ __launch_bounds__(256) void cvt_all(
    const float* __restrict__ x,  _Float16* __restrict__ xh,
    const float* __restrict__ Wq, _Float16* __restrict__ wqh,
    const float* __restrict__ Wk, _Float16* __restrict__ wkh,
    const float* __restrict__ Wv, _Float16* __restrict__ wvh,
    float* __restrict__ Vtail) {
  int bid = blockIdx.x;
  if (bid >= 7168) {                    // 4 blocks zero Vtail (B*H*HD f32)
    int i = (bid - 7168) * 1024 + threadIdx.x * 4;
    *(float4*)(Vtail + i) = make_float4(0.f, 0.f, 0.f, 0.f);
    return;
  }
  const float* src; _Float16* dst; int base;
  if (bid < 4096)      { src = x;  dst = xh;  base = bid; }
  else if (bid < 5120) { src = Wq; dst = wqh; base = bid - 4096; }
  else if (bid < 6144) { src = Wk; dst = wkh; base = bid - 5120; }
  else                 { src = Wv; dst = wvh; base = bid - 6144; }
  int i = base * 1024 + threadIdx.x * 4;
  float4 f = *(const float4*)(src + i);
  f16x4 h;
  h.x = (_Float16)f.x; h.y = (_Float16)f.y; h.z = (_Float16)f.z; h.w = (_Float16)f.w;
  *(f16x4*)(dst + i) = h;
}

// ---------------------------------------------- GEMM 128x64, BK=64 (gemm1) ---
// R8-VERIFIED; only change: launch_bounds 2->3 waves/EU (3 blocks/CU) so a
// third independent block's MFMA overlaps the other blocks' vmcnt(0) drains.
__global__ __launch_bounds__(256, 3) void gemm_bt_bias(
    const _Float16* __restrict__ A,
    const _Float16* __restrict__ B0, const float* __restrict__ bias0,
    _Float16* __restrict__ C0,
    const _Float16* __restrict__ B1, const float* __restrict__ bias1,
    _Float16* __restrict__ C1,
    int M, int N, int K)
{
  const _Float16* Bm = blockIdx.z ? B1 : B0;
  const float* bias  = blockIdx.z ? bias1 : bias0;
  _Float16* C        = blockIdx.z ? C1 : C0;

  __shared__ _Float16 As[2 * 128 * 32];   // 16 KB
  __shared__ _Float16 Bs[2 * 64 * 32];    //  8 KB

  int tid  = threadIdx.x;
  int lane = tid & 63;
  int wave = tid >> 6;
  int wm = wave >> 1, wn = wave & 1;
  int qd = lane >> 4, l15 = lane & 15;

  long row0 = (long)blockIdx.y * 128;
  long col0 = (long)blockIdx.x * 64;

  int r_a = tid >> 2;
  int c_a = (tid & 3) * 8;

  f32x4 acc[4][2] = {};

  for (int kk = 0; kk < K; kk += 64) {
    GLD16(A  + (row0 + r_a) * K + kk + c_a,           As + tid * 8);
    GLD16(A  + (row0 + 64 + r_a) * K + kk + c_a,      As + 2048 + tid * 8);
    GLD16(A  + (row0 + r_a) * K + kk + 32 + c_a,      As + 4096 + tid * 8);
    GLD16(A  + (row0 + 64 + r_a) * K + kk + 32 + c_a, As + 6144 + tid * 8);
    GLD16(Bm + (col0 + r_a) * K + kk + c_a,           Bs + tid * 8);
    GLD16(Bm + (col0 + r_a) * K + kk + 32 + c_a,      Bs + 2048 + tid * 8);
    __syncthreads();

    for (int ks = 0; ks < 2; ks++) {
      f16x8 af[4], bfr[2];
      for (int t = 0; t < 4; t++)
        af[t]  = *(const f16x8*)(As + ks * 4096 + (wm * 64 + t * 16 + l15) * 32 + qd * 8);
      for (int j = 0; j < 2; j++)
        bfr[j] = *(const f16x8*)(Bs + ks * 2048 + (wn * 32 + j * 16 + l15) * 32 + qd * 8);
      for (int i = 0; i < 4; i++)
        for (int j = 0; j < 2; j++)
          acc[i][j] = __builtin_amdgcn_mfma_f32_16x16x32_f16(af[i], bfr[j], acc[i][j], 0, 0, 0);
    }
    __syncthreads();
  }

  for (int i = 0; i < 4; i++) {
    long row = row0 + wm * 64 + i * 16 + qd * 4;
    for (int j = 0; j < 2; j++) {
      long col = col0 + wn * 32 + j * 16 + l15;
      float bv = bias[col];
      for (int r = 0; r < 4; r++)
        C[(row + r) * N + col] = (_Float16)(acc[i][j][r] + bv);
    }
  }
}

// --------------------------------------------- GEMM 128x128, BK=64 (gemm2) ---
// R8-VERIFIED; only change: launch_bounds 2->3 (32 KB LDS -> 5 blocks LDS-max).
__global__ __launch_bounds__(256, 3) void gemm_bt_bias128(
    const _Float16* __restrict__ A,
    const _Float16* __restrict__ B0, const float* __restrict__ bias0,
    _Float16* __restrict__ C0,
    const _Float16* __restrict__ B1, const float* __restrict__ bias1,
    _Float16* __restrict__ C1,
    int M, int N, int K)
{
  const _Float16* Bm = blockIdx.z ? B1 : B0;
  const float* bias  = blockIdx.z ? bias1 : bias0;
  _Float16* C        = blockIdx.z ? C1 : C0;

  __shared__ _Float16 As[2 * 128 * 32];   // 16 KB
  __shared__ _Float16 Bs[2 * 128 * 32];   // 16 KB

  int tid  = threadIdx.x;
  int lane = tid & 63;
  int wave = tid >> 6;
  int wm = wave >> 1, wn = wave & 1;
  int qd = lane >> 4, l15 = lane & 15;

  long row0 = (long)blockIdx.y * 128;
  long col0 = (long)blockIdx.x * 128;

  int r_a = tid >> 2;
  int c_a = (tid & 3) * 8;

  f32x4 acc[4][4] = {};

  for (int kk = 0; kk < K; kk += 64) {
    GLD16(A  + (row0 + r_a) * K + kk + c_a,           As + tid * 8);
    GLD16(A  + (row0 + 64 + r_a) * K + kk + c_a,      As + 2048 + tid * 8);
    GLD16(A  + (row0 + r_a) * K + kk + 32 + c_a,      As + 4096 + tid * 8);
    GLD16(A  + (row0 + 64 + r_a) * K + kk + 32 + c_a, As + 6144 + tid * 8);
    GLD16(Bm + (col0 + r_a) * K + kk + c_a,           Bs + tid * 8);
    GLD16(Bm + (col0 + 64 + r_a) * K + kk + c_a,      Bs + 2048 + tid * 8);
    GLD16(Bm + (col0 + r_a) * K + kk + 32 + c_a,      Bs + 4096 + tid * 8);
    GLD16(Bm + (col0 + 64 + r_a) * K + kk + 32 + c_a, Bs + 6144 + tid * 8);
    __syncthreads();

    for (int ks = 0; ks < 2; ks++) {
      f16x8 af[4], bfr[4];
      for (int t = 0; t < 4; t++) {
        af[t]  = *(const f16x8*)(As + ks * 4096 + (wm * 64 + t * 16 + l15) * 32 + qd * 8);
        bfr[t] = *(const f16x8*)(Bs + ks * 4096 + (wn * 64 + t * 16 + l15) * 32 + qd * 8);
      }
      for (int i = 0; i < 4; i++)
        for (int j = 0; j < 4; j++)
          acc[i][j] = __builtin_amdgcn_mfma_f32_16x16x32_f16(af[i], bfr[j], acc[i][j], 0, 0, 0);
    }
    __syncthreads();
  }

  for (int i = 0; i < 4; i++) {
    long row = row0 + wm * 64 + i * 16 + qd * 4;
    for (int j = 0; j < 4; j++) {
      long col = col0 + wn * 64 + j * 16 + l15;
      float bv = bias[col];
      for (int r = 0; r < 4; r++)
        C[(row + r) * N + col] = (_Float16)(acc[i][j][r] + bv);
    }
  }
}

// ----------------------------------------------------------------- LN qkv ---
// R5-VERIFIED body; launch_bounds 2->4 (VGPR ~60, LDS 35 KB -> 4 blocks/CU).
__global__ __launch_bounds__(256, 4) void ln_qkv(
    const _Float16* __restrict__ qh,
    const _Float16* __restrict__ kh,
    const _Float16* __restrict__ vh,
    const float* __restrict__ ln_g, const float* __restrict__ ln_b,
    const int* __restrict__ seq_len,
    _Float16* __restrict__ Qn,
    _Float16* __restrict__ Kn,
    unsigned short* __restrict__ Vt,
    float* __restrict__ Vtail)
{
  __shared__ unsigned short Vls[256][68];   // bf16, padded ~34 KB
  int tid = threadIdx.x;
  int s0 = blockIdx.x * 256;
  int h = blockIdx.y, b = blockIdx.z;
  long bh = (long)b * H_ + h;
  long s = s0 + tid;
  long inbase  = ((long)b * S_ + s) * D_ + (long)h * HD_;
  long outbase = (bh * S_ + s) * HD_;

  f16x8 rw[8];
  // ---- q ----
  {
    for (int i = 0; i < 8; i++) rw[i] = *(const f16x8*)(qh + inbase + i * 8);
    float sum = 0.f, sq = 0.f;
    for (int i = 0; i < 8; i++)
      for (int j = 0; j < 8; j++) { float xv = (float)rw[i][j]; sum += xv; sq = fmaf(xv, xv, sq); }
    float m = sum * (1.f / 64.f);
    float inv = rsqrtf(sq * (1.f / 64.f) - m * m + EPS_);
    for (int i = 0; i < 8; i++) {
      f16x8 o;
      for (int j = 0; j < 8; j++)
        o[j] = (_Float16)(((float)rw[i][j] - m) * inv * ln_g[i * 8 + j] + ln_b[i * 8 + j]);
      *(f16x8*)(Qn + outbase + i * 8) = o;
    }
  }
  // ---- k ----
  {
    for (int i = 0; i < 8; i++) rw[i] = *(const f16x8*)(kh + inbase + i * 8);
    float sum = 0.f, sq = 0.f;
    for (int i = 0; i < 8; i++)
      for (int j = 0; j < 8; j++) { float xv = (float)rw[i][j]; sum += xv; sq = fmaf(xv, xv, sq); }
    float m = sum * (1.f / 64.f);
    float inv = rsqrtf(sq * (1.f / 64.f) - m * m + EPS_);
    for (int i = 0; i < 8; i++) {
      f16x8 o;
      for (int j = 0; j < 8; j++)
        o[j] = (_Float16)(((float)rw[i][j] - m) * inv * ln_g[i * 8 + j] + ln_b[i * 8 + j]);
      *(f16x8*)(Kn + outbase + i * 8) = o;
    }
  }
  // ---- v (normalize to bf16 into LDS, then transposed write-out) ----
  {
    for (int i = 0; i < 8; i++) rw[i] = *(const f16x8*)(vh + inbase + i * 8);
    float sum = 0.f, sq = 0.f;
    for (int i = 0; i < 8; i++)
      for (int j = 0; j < 8; j++) { float xv = (float)rw[i][j]; sum += xv; sq = fmaf(xv, xv, sq); }
    float m = sum * (1.f / 64.f);
    float inv = rsqrtf(sq * (1.f / 64.f) - m * m + EPS_);
    for (int i = 0; i < 8; i++)
      for (int j = 0; j < 8; j++)
        Vls[tid][i * 8 + j] = f2bf(((float)rw[i][j] - m) * inv * ln_g[i * 8 + j] + ln_b[i * 8 + j]);
  }
  __syncthreads();
  int d = tid >> 2, sc = tid & 3;
  int len = seq_len[b];
  long vbase = (bh * HD_ + d) * S_ + s0 + sc * 64;
  float tsum = 0.f;
  for (int j0 = 0; j0 < 64; j0 += 8) {
    ushort8v w;
    for (int jj = 0; jj < 8; jj++) {
      unsigned short ub = Vls[sc * 64 + j0 + jj][d];
      w[jj] = ub;
      if (s0 + sc * 64 + j0 + jj >= len) tsum += bf2f(ub);
    }
    *(ushort8v*)(Vt + vbase + j0) = w;
  }
  if (s0 + sc * 64 + 64 > len)            // any tail rows in this chunk
    atomicAdd(&Vtail[bh * HD_ + d], tsum);
}

// -------------------------------------------------------------- attention ---
// R6/R7-VERIFIED body; launch_bounds 2->4 (VGPR=40 measured, LDS 34 KB ->
// 4 blocks/CU) — doubles the wave pool hiding the exp/LDS-write VALU chain.
__global__ __launch_bounds__(256, 4) void attn(
    const _Float16* __restrict__ Qn,
    const _Float16* __restrict__ Kn,
    const unsigned short* __restrict__ Vt,
    const float* __restrict__ Vtail,
    const int* __restrict__ seq_len,
    float* __restrict__ out)
{
  __shared__ _Float16 Ks[2][64 * 32];        // [d-half][key][32]    8 KB
  __shared__ unsigned short Vts[2][64 * 32]; // [key-half][d][32]    8 KB
  __shared__ unsigned short Ps[4][32 * 72];  // per-wave P [32m][72] 18 KB

  int tid = threadIdx.x, lane = tid & 63, wave = tid >> 6;
  int qd = lane >> 4, l15 = lane & 15;
  int b = blockIdx.x;                        // b fastest: len load-balance
  int h = blockIdx.y;
  int q0 = blockIdx.z * 128;
  long bh = (long)b * H_ + h;
  int len = seq_len[b];
  int ntile = (len + 63) >> 6;               // tiles containing any key < len

  int skey = tid >> 2;
  int schunk = (tid & 3) * 8;

  f16x8 qf[2][2];
  for (int mt = 0; mt < 2; mt++) {
    const _Float16* qp = Qn + (bh * S_ + q0 + wave * 32 + mt * 16 + l15) * HD_;
    qf[mt][0] = *(const f16x8*)(qp + qd * 8);
    qf[mt][1] = *(const f16x8*)(qp + 32 + qd * 8);
  }
  float tv[4];
  for (int t = 0; t < 4; t++) tv[t] = Vtail[bh * HD_ + t * 16 + l15];

  f32x4 o[2][4] = {};
  float den[2][4] = {{0.f,0.f,0.f,0.f},{0.f,0.f,0.f,0.f}};

  for (int kt = 0; kt < ntile; kt++) {
    GLD16(Kn + (bh * S_ + kt * 64 + skey) * HD_ + schunk,      &Ks[0][0] + tid * 8);
    GLD16(Kn + (bh * S_ + kt * 64 + skey) * HD_ + 32 + schunk, &Ks[1][0] + tid * 8);
    GLD16(Vt + (bh * HD_ + skey) * S_ + kt * 64 + schunk,      &Vts[0][0] + tid * 8);
    GLD16(Vt + (bh * HD_ + skey) * S_ + kt * 64 + 32 + schunk, &Vts[1][0] + tid * 8);
    __syncthreads();

    f32x4 sacc[2][4] = {};
    for (int tn = 0; tn < 4; tn++) {
      f16x8 kf0 = *(const f16x8*)(&Ks[0][0] + (tn * 16 + l15) * 32 + qd * 8);
      f16x8 kf1 = *(const f16x8*)(&Ks[1][0] + (tn * 16 + l15) * 32 + qd * 8);
      for (int mt = 0; mt < 2; mt++) {
        sacc[mt][tn] = __builtin_amdgcn_mfma_f32_16x16x32_f16(qf[mt][0], kf0, sacc[mt][tn], 0, 0, 0);
        sacc[mt][tn] = __builtin_amdgcn_mfma_f32_16x16x32_f16(qf[mt][1], kf1, sacc[mt][tn], 0, 0, 0);
      }
    }

    for (int mt = 0; mt < 2; mt++)
      for (int tn = 0; tn < 4; tn++) {
        int kg = kt * 64 + tn * 16 + l15;
        for (int r = 0; r < 4; r++) {
          float p = (kg < len) ? __expf(sacc[mt][tn][r]) : 0.f;
          unsigned short pb = f2bf(p);
          den[mt][r] += bf2f(pb);
          Ps[wave][(mt * 16 + qd * 4 + r) * 72 + tn * 16 + l15] = pb;
        }
      }

    bf16x8 pf[2][2];
    for (int mt = 0; mt < 2; mt++) {
      pf[mt][0] = *(const bf16x8*)(&Ps[wave][(mt * 16 + l15) * 72 + qd * 8]);
      pf[mt][1] = *(const bf16x8*)(&Ps[wave][(mt * 16 + l15) * 72 + 32 + qd * 8]);
    }
    for (int t = 0; t < 4; t++) {
      bf16x8 vf0 = *(const bf16x8*)(&Vts[0][0] + (t * 16 + l15) * 32 + qd * 8);
      bf16x8 vf1 = *(const bf16x8*)(&Vts[1][0] + (t * 16 + l15) * 32 + qd * 8);
      for (int mt = 0; mt < 2; mt++) {
        o[mt][t] = __builtin_amdgcn_mfma_f32_16x16x32_bf16(pf[mt][0], vf0, o[mt][t], 0, 0, 0);
        o[mt][t] = __builtin_amdgcn_mfma_f32_16x16x32_bf16(pf[mt][1], vf1, o[mt][t], 0, 0, 0);
      }
    }
    __syncthreads();
  }

  for (int mt = 0; mt < 2; mt++)
    for (int t = 0; t < 4; t++)
      for (int r = 0; r < 4; r++) o[mt][t][r] += tv[t];

  float tden = (float)(S_ - len);
  for (int mt = 0; mt < 2; mt++)
    for (int r = 0; r < 4; r++) {
      for (int off = 1; off < 16; off <<= 1)
        den[mt][r] += __shfl_xor(den[mt][r], off, 64);
      den[mt][r] += tden;
    }

  for (int mt = 0; mt < 2; mt++)
    for (int t = 0; t < 4; t++)
      for (int r = 0; r < 4; r++) {
        long s = q0 + wave * 32 + mt * 16 + qd * 4 + r;
        long dcol = (long)h * HD_ + t * 16 + l15;
        out[((long)b * S_ + s) * D_ + dcol] = o[mt][t][r] / den[mt][r];
      }
}

// ----------------------------------------------------------------- launch ---
extern "C" void kernel_launch(void* const* d_in, const int* in_sizes, int n_in,
                              void* d_out, int out_size, void* d_ws, size_t ws_size,
                              hipStream_t stream) {
  const float* x     = (const float*)d_in[0];
  const int*  seq    = (const int*)d_in[1];
  const float* Wq    = (const float*)d_in[2];
  const float* bq    = (const float*)d_in[3];
  const float* Wk    = (const float*)d_in[4];
  const float* bk    = (const float*)d_in[5];
  const float* Wv    = (const float*)d_in[6];
  const float* bv    = (const float*)d_in[7];
  const float* ln_g  = (const float*)d_in[8];
  const float* ln_b  = (const float*)d_in[9];
  float* out = (float*)d_out;

  char* ws = (char*)d_ws;
  _Float16* xh  = (_Float16*)(ws);                          // 8 MB
  _Float16* wqh = (_Float16*)(ws + (8l  << 20));            // 2 MB
  _Float16* wkh = (_Float16*)(ws + (10l << 20));            // 2 MB
  _Float16* wvh = (_Float16*)(ws + (12l << 20));            // 2 MB
  float*    Vtail = (float*)(ws + (14l << 20));             // 16 KB
  _Float16* qh  = (_Float16*)(ws + (16l << 20));            // 8 MB
  _Float16* kh  = (_Float16*)(ws + (24l << 20));            // 8 MB
  _Float16* vh  = (_Float16*)(ws + (32l << 20));            // 8 MB
  _Float16* Qn  = (_Float16*)(ws + (40l << 20));            // 8 MB
  _Float16* Kn  = (_Float16*)(ws + (48l << 20));            // 8 MB
  unsigned short* Vt = (unsigned short*)(ws + (56l << 20)); // 8 MB

  cvt_all<<<7172, 256, 0, stream>>>(x, xh, Wq, wqh, Wk, wkh, Wv, wvh, Vtail);

  dim3 g1(D_ / 64, (B_ * S_) / 128, 1);
  gemm_bt_bias<<<g1, 256, 0, stream>>>(xh, wqh, bq, qh, wqh, bq, qh,
                                       B_ * S_, D_, D_);
  dim3 g2(D_ / 128, (B_ * S_) / 128, 2);
  gemm_bt_bias128<<<g2, 256, 0, stream>>>(qh, wkh, bk, kh, wvh, bv, vh,
                                          B_ * S_, D_, D_);

  dim3 g3(S_ / 256, H_, B_);
  ln_qkv<<<g3, 256, 0, stream>>>(qh, kh, vh, ln_g, ln_b, seq, Qn, Kn, Vt, Vtail);

  dim3 g4(B_, H_, S_ / 128);
  attn<<<g4, 256, 0, stream>>>(Qn, Kn, Vt, Vtail, seq, out);
}

// Round 11
// 188.900 us; speedup vs baseline: 1.1004x; 1.1004x over previous
//
#include <hip/hip_runtime.h>

#define B_  4
#define S_  1024
#define D_  1024
#define H_  16
#define HD_ 64
#define EPS_ 1e-5f

typedef _Float16 f16x8 __attribute__((ext_vector_type(8)));
typedef _Float16 f16x4 __attribute__((ext_vector_type(4)));
typedef __bf16 bf16x8 __attribute__((ext_vector_type(8)));
typedef float  f32x4  __attribute__((ext_vector_type(4)));
typedef unsigned short ushort8v __attribute__((ext_vector_type(8)));

static __device__ __forceinline__ unsigned short f2bf(float f) {
  union { float f; unsigned u; } v; v.f = f;
  unsigned r = v.u + 0x7fffu + ((v.u >> 16) & 1u);
  return (unsigned short)(r >> 16);
}
static __device__ __forceinline__ float bf2f(unsigned short u) {
  union { unsigned u; float f; } v; v.u = ((unsigned)u) << 16;
  return v.f;
}

// async global->LDS, 16B per lane; LDS dest is wave-uniform base + lane*16
#define GLD16(gp, lp) __builtin_amdgcn_global_load_lds( \
    (const __attribute__((address_space(1))) void*)(gp), \
    (__attribute__((address_space(3))) void*)(lp), 16, 0, 0)

// ---------------------------------------------------------------- convert ---
__global__ __launch_bounds__(256) void cvt_all(
    const float* __restrict__ x,  _Float16* __restrict__ xh,
    const float* __restrict__ Wq, _Float16* __restrict__ wqh,
    const float* __restrict__ Wk, _Float16* __restrict__ wkh,
    const float* __restrict__ Wv, _Float16* __restrict__ wvh,
    float* __restrict__ Vtail) {
  int bid = blockIdx.x;
  if (bid >= 7168) {                    // 4 blocks zero Vtail (B*H*HD f32)
    int i = (bid - 7168) * 1024 + threadIdx.x * 4;
    *(float4*)(Vtail + i) = make_float4(0.f, 0.f, 0.f, 0.f);
    return;
  }
  const float* src; _Float16* dst; int base;
  if (bid < 4096)      { src = x;  dst = xh;  base = bid; }
  else if (bid < 5120) { src = Wq; dst = wqh; base = bid - 4096; }
  else if (bid < 6144) { src = Wk; dst = wkh; base = bid - 5120; }
  else                 { src = Wv; dst = wvh; base = bid - 6144; }
  int i = base * 1024 + threadIdx.x * 4;
  float4 f = *(const float4*)(src + i);
  f16x4 h;
  h.x = (_Float16)f.x; h.y = (_Float16)f.y; h.z = (_Float16)f.z; h.w = (_Float16)f.w;
  *(f16x4*)(dst + i) = h;
}

// ---------------------------------------------- GEMM 128x64, BK=64 (gemm1) ---
// R9-VERIFIED verbatim (bounds back to 2 — R10's 3 caused spill-squeeze).
__global__ __launch_bounds__(256, 2) void gemm_bt_bias(
    const _Float16* __restrict__ A,
    const _Float16* __restrict__ B0, const float* __restrict__ bias0,
    _Float16* __restrict__ C0,
    const _Float16* __restrict__ B1, const float* __restrict__ bias1,
    _Float16* __restrict__ C1,
    int M, int N, int K)
{
  const _Float16* Bm = blockIdx.z ? B1 : B0;
  const float* bias  = blockIdx.z ? bias1 : bias0;
  _Float16* C        = blockIdx.z ? C1 : C0;

  __shared__ _Float16 As[2 * 128 * 32];   // 16 KB
  __shared__ _Float16 Bs[2 * 64 * 32];    //  8 KB

  int tid  = threadIdx.x;
  int lane = tid & 63;
  int wave = tid >> 6;
  int wm = wave >> 1, wn = wave & 1;
  int qd = lane >> 4, l15 = lane & 15;

  long row0 = (long)blockIdx.y * 128;
  long col0 = (long)blockIdx.x * 64;

  int r_a = tid >> 2;
  int c_a = (tid & 3) * 8;

  f32x4 acc[4][2] = {};

  for (int kk = 0; kk < K; kk += 64) {
    GLD16(A  + (row0 + r_a) * K + kk + c_a,           As + tid * 8);
    GLD16(A  + (row0 + 64 + r_a) * K + kk + c_a,      As + 2048 + tid * 8);
    GLD16(A  + (row0 + r_a) * K + kk + 32 + c_a,      As + 4096 + tid * 8);
    GLD16(A  + (row0 + 64 + r_a) * K + kk + 32 + c_a, As + 6144 + tid * 8);
    GLD16(Bm + (col0 + r_a) * K + kk + c_a,           Bs + tid * 8);
    GLD16(Bm + (col0 + r_a) * K + kk + 32 + c_a,      Bs + 2048 + tid * 8);
    __syncthreads();

    for (int ks = 0; ks < 2; ks++) {
      f16x8 af[4], bfr[2];
      for (int t = 0; t < 4; t++)
        af[t]  = *(const f16x8*)(As + ks * 4096 + (wm * 64 + t * 16 + l15) * 32 + qd * 8);
      for (int j = 0; j < 2; j++)
        bfr[j] = *(const f16x8*)(Bs + ks * 2048 + (wn * 32 + j * 16 + l15) * 32 + qd * 8);
      for (int i = 0; i < 4; i++)
        for (int j = 0; j < 2; j++)
          acc[i][j] = __builtin_amdgcn_mfma_f32_16x16x32_f16(af[i], bfr[j], acc[i][j], 0, 0, 0);
    }
    __syncthreads();
  }

  for (int i = 0; i < 4; i++) {
    long row = row0 + wm * 64 + i * 16 + qd * 4;
    for (int j = 0; j < 2; j++) {
      long col = col0 + wn * 32 + j * 16 + l15;
      float bv = bias[col];
      for (int r = 0; r < 4; r++)
        C[(row + r) * N + col] = (_Float16)(acc[i][j][r] + bv);
    }
  }
}

// --------------------------------------------- GEMM 128x128, BK=64 (gemm2) ---
// R9-VERIFIED verbatim (bounds back to 2).
__global__ __launch_bounds__(256, 2) void gemm_bt_bias128(
    const _Float16* __restrict__ A,
    const _Float16* __restrict__ B0, const float* __restrict__ bias0,
    _Float16* __restrict__ C0,
    const _Float16* __restrict__ B1, const float* __restrict__ bias1,
    _Float16* __restrict__ C1,
    int M, int N, int K)
{
  const _Float16* Bm = blockIdx.z ? B1 : B0;
  const float* bias  = blockIdx.z ? bias1 : bias0;
  _Float16* C        = blockIdx.z ? C1 : C0;

  __shared__ _Float16 As[2 * 128 * 32];   // 16 KB
  __shared__ _Float16 Bs[2 * 128 * 32];   // 16 KB

  int tid  = threadIdx.x;
  int lane = tid & 63;
  int wave = tid >> 6;
  int wm = wave >> 1, wn = wave & 1;
  int qd = lane >> 4, l15 = lane & 15;

  long row0 = (long)blockIdx.y * 128;
  long col0 = (long)blockIdx.x * 128;

  int r_a = tid >> 2;
  int c_a = (tid & 3) * 8;

  f32x4 acc[4][4] = {};

  for (int kk = 0; kk < K; kk += 64) {
    GLD16(A  + (row0 + r_a) * K + kk + c_a,           As + tid * 8);
    GLD16(A  + (row0 + 64 + r_a) * K + kk + c_a,      As + 2048 + tid * 8);
    GLD16(A  + (row0 + r_a) * K + kk + 32 + c_a,      As + 4096 + tid * 8);
    GLD16(A  + (row0 + 64 + r_a) * K + kk + 32 + c_a, As + 6144 + tid * 8);
    GLD16(Bm + (col0 + r_a) * K + kk + c_a,           Bs + tid * 8);
    GLD16(Bm + (col0 + 64 + r_a) * K + kk + c_a,      Bs + 2048 + tid * 8);
    GLD16(Bm + (col0 + r_a) * K + kk + 32 + c_a,      Bs + 4096 + tid * 8);
    GLD16(Bm + (col0 + 64 + r_a) * K + kk + 32 + c_a, Bs + 6144 + tid * 8);
    __syncthreads();

    for (int ks = 0; ks < 2; ks++) {
      f16x8 af[4], bfr[4];
      for (int t = 0; t < 4; t++) {
        af[t]  = *(const f16x8*)(As + ks * 4096 + (wm * 64 + t * 16 + l15) * 32 + qd * 8);
        bfr[t] = *(const f16x8*)(Bs + ks * 4096 + (wn * 64 + t * 16 + l15) * 32 + qd * 8);
      }
      for (int i = 0; i < 4; i++)
        for (int j = 0; j < 4; j++)
          acc[i][j] = __builtin_amdgcn_mfma_f32_16x16x32_f16(af[i], bfr[j], acc[i][j], 0, 0, 0);
    }
    __syncthreads();
  }

  for (int i = 0; i < 4; i++) {
    long row = row0 + wm * 64 + i * 16 + qd * 4;
    for (int j = 0; j < 4; j++) {
      long col = col0 + wn * 64 + j * 16 + l15;
      float bv = bias[col];
      for (int r = 0; r < 4; r++)
        C[(row + r) * N + col] = (_Float16)(acc[i][j][r] + bv);
    }
  }
}

// ------------------------------------------------------------- LN qkv v2 ---
// REWRITE: R10 profile showed 46.6 us, 1.67 TB/s, Occ 8% — 256 blocks =
// 1 blk/CU and per-thread strided 16B loads were latency-bound. Now: 64-row
// tiles -> grid 16*16*4 = 1024 blocks (4/CU), GLD16-staged tiles (attn's
// verified dense-tiling LDS pattern), 4 lanes/row + 2-step shuffle reduce.
// Thread (w,l): row = w*16 + (l&15), quarter a = l>>4; lane handles cols
// [a*8,a*8+8) of each 32-col half. Reduction across a: shfl_xor 16,32.
__global__ __launch_bounds__(256, 4) void ln_qkv(
    const _Float16* __restrict__ qh,
    const _Float16* __restrict__ kh,
    const _Float16* __restrict__ vh,
    const float* __restrict__ ln_g, const float* __restrict__ ln_b,
    const int* __restrict__ seq_len,
    _Float16* __restrict__ Qn,
    _Float16* __restrict__ Kn,
    unsigned short* __restrict__ Vt,
    float* __restrict__ Vtail)
{
  __shared__ _Float16 Qs[2][64 * 32];       // 8 KB
  __shared__ _Float16 Ks_[2][64 * 32];      // 8 KB
  __shared__ _Float16 Vs[2][64 * 32];       // 8 KB
  __shared__ unsigned short Vls[64][68];    // 8.5 KB (transpose stage)

  int tid = threadIdx.x, lane = tid & 63, w = tid >> 6;
  int a = lane >> 4, r16 = lane & 15;
  int row = w * 16 + r16;                   // 0..63
  int s0 = blockIdx.x * 64;
  int h = blockIdx.y, b = blockIdx.z;
  long bh = (long)b * H_ + h;
  int len = seq_len[b];

  // staged load (coalesced 64B/4-lane segments)
  int skey = tid >> 2, schunk = (tid & 3) * 8;
  long gbase = ((long)b * S_ + s0 + skey) * D_ + (long)h * HD_ + schunk;
  GLD16(qh + gbase,      &Qs[0][0] + tid * 8);
  GLD16(qh + gbase + 32, &Qs[1][0] + tid * 8);
  GLD16(kh + gbase,      &Ks_[0][0] + tid * 8);
  GLD16(kh + gbase + 32, &Ks_[1][0] + tid * 8);
  GLD16(vh + gbase,      &Vs[0][0] + tid * 8);
  GLD16(vh + gbase + 32, &Vs[1][0] + tid * 8);

  float g0[8], bb0[8], g1[8], bb1[8];
  for (int u = 0; u < 8; u++) {
    g0[u] = ln_g[a * 8 + u];       bb0[u] = ln_b[a * 8 + u];
    g1[u] = ln_g[32 + a * 8 + u];  bb1[u] = ln_b[32 + a * 8 + u];
  }
  __syncthreads();

  long obase = (bh * S_ + s0 + row) * HD_;

  // ---- q ----
  {
    f16x8 x0 = *(const f16x8*)(&Qs[0][row * 32 + a * 8]);
    f16x8 x1 = *(const f16x8*)(&Qs[1][row * 32 + a * 8]);
    float sum = 0.f, sq = 0.f;
    for (int u = 0; u < 8; u++) {
      float v0 = (float)x0[u], v1 = (float)x1[u];
      sum += v0 + v1; sq = fmaf(v0, v0, fmaf(v1, v1, sq));
    }
    for (int off = 16; off < 64; off <<= 1) {
      sum += __shfl_xor(sum, off, 64); sq += __shfl_xor(sq, off, 64);
    }
    float m = sum * (1.f / 64.f);
    float inv = rsqrtf(sq * (1.f / 64.f) - m * m + EPS_);
    f16x8 o0, o1;
    for (int u = 0; u < 8; u++) {
      o0[u] = (_Float16)(((float)x0[u] - m) * inv * g0[u] + bb0[u]);
      o1[u] = (_Float16)(((float)x1[u] - m) * inv * g1[u] + bb1[u]);
    }
    *(f16x8*)(Qn + obase + a * 8) = o0;
    *(f16x8*)(Qn + obase + 32 + a * 8) = o1;
  }
  // ---- k ----
  {
    f16x8 x0 = *(const f16x8*)(&Ks_[0][row * 32 + a * 8]);
    f16x8 x1 = *(const f16x8*)(&Ks_[1][row * 32 + a * 8]);
    float sum = 0.f, sq = 0.f;
    for (int u = 0; u < 8; u++) {
      float v0 = (float)x0[u], v1 = (float)x1[u];
      sum += v0 + v1; sq = fmaf(v0, v0, fmaf(v1, v1, sq));
    }
    for (int off = 16; off < 64; off <<= 1) {
      sum += __shfl_xor(sum, off, 64); sq += __shfl_xor(sq, off, 64);
    }
    float m = sum * (1.f / 64.f);
    float inv = rsqrtf(sq * (1.f / 64.f) - m * m + EPS_);
    f16x8 o0, o1;
    for (int u = 0; u < 8; u++) {
      o0[u] = (_Float16)(((float)x0[u] - m) * inv * g0[u] + bb0[u]);
      o1[u] = (_Float16)(((float)x1[u] - m) * inv * g1[u] + bb1[u]);
    }
    *(f16x8*)(Kn + obase + a * 8) = o0;
    *(f16x8*)(Kn + obase + 32 + a * 8) = o1;
  }
  // ---- v (normalize to bf16 into Vls transpose stage) ----
  {
    f16x8 x0 = *(const f16x8*)(&Vs[0][row * 32 + a * 8]);
    f16x8 x1 = *(const f16x8*)(&Vs[1][row * 32 + a * 8]);
    float sum = 0.f, sq = 0.f;
    for (int u = 0; u < 8; u++) {
      float v0 = (float)x0[u], v1 = (float)x1[u];
      sum += v0 + v1; sq = fmaf(v0, v0, fmaf(v1, v1, sq));
    }
    for (int off = 16; off < 64; off <<= 1) {
      sum += __shfl_xor(sum, off, 64); sq += __shfl_xor(sq, off, 64);
    }
    float m = sum * (1.f / 64.f);
    float inv = rsqrtf(sq * (1.f / 64.f) - m * m + EPS_);
    for (int u = 0; u < 8; u++) {
      Vls[row][a * 8 + u]      = f2bf(((float)x0[u] - m) * inv * g0[u] + bb0[u]);
      Vls[row][32 + a * 8 + u] = f2bf(((float)x1[u] - m) * inv * g1[u] + bb1[u]);
    }
  }
  __syncthreads();

  // transposed write-out: thread -> (d = tid>>2, s-chunk = (tid&3)*16)
  int d = tid >> 2, sc = tid & 3;
  long vbase = (bh * HD_ + d) * S_ + s0 + sc * 16;
  float tsum = 0.f;
  ushort8v w0, w1;
  for (int j = 0; j < 8; j++) {
    unsigned short ub = Vls[sc * 16 + j][d];
    w0[j] = ub;
    if (s0 + sc * 16 + j >= len) tsum += bf2f(ub);
  }
  for (int j = 0; j < 8; j++) {
    unsigned short ub = Vls[sc * 16 + 8 + j][d];
    w1[j] = ub;
    if (s0 + sc * 16 + 8 + j >= len) tsum += bf2f(ub);
  }
  *(ushort8v*)(Vt + vbase) = w0;
  *(ushort8v*)(Vt + vbase + 8) = w1;
  if (s0 + sc * 16 + 16 > len)            // any tail rows in this chunk
    atomicAdd(&Vtail[bh * HD_ + d], tsum);
}

// -------------------------------------------------------------- attention ---
// R9-VERIFIED verbatim (bounds back to 2).
__global__ __launch_bounds__(256, 2) void attn(
    const _Float16* __restrict__ Qn,
    const _Float16* __restrict__ Kn,
    const unsigned short* __restrict__ Vt,
    const float* __restrict__ Vtail,
    const int* __restrict__ seq_len,
    float* __restrict__ out)
{
  __shared__ _Float16 Ks[2][64 * 32];        // [d-half][key][32]    8 KB
  __shared__ unsigned short Vts[2][64 * 32]; // [key-half][d][32]    8 KB
  __shared__ unsigned short Ps[4][32 * 72];  // per-wave P [32m][72] 18 KB

  int tid = threadIdx.x, lane = tid & 63, wave = tid >> 6;
  int qd = lane >> 4, l15 = lane & 15;
  int b = blockIdx.x;                        // b fastest: len load-balance
  int h = blockIdx.y;
  int q0 = blockIdx.z * 128;
  long bh = (long)b * H_ + h;
  int len = seq_len[b];
  int ntile = (len + 63) >> 6;               // tiles containing any key < len

  int skey = tid >> 2;
  int schunk = (tid & 3) * 8;

  f16x8 qf[2][2];
  for (int mt = 0; mt < 2; mt++) {
    const _Float16* qp = Qn + (bh * S_ + q0 + wave * 32 + mt * 16 + l15) * HD_;
    qf[mt][0] = *(const f16x8*)(qp + qd * 8);
    qf[mt][1] = *(const f16x8*)(qp + 32 + qd * 8);
  }
  float tv[4];
  for (int t = 0; t < 4; t++) tv[t] = Vtail[bh * HD_ + t * 16 + l15];

  f32x4 o[2][4] = {};
  float den[2][4] = {{0.f,0.f,0.f,0.f},{0.f,0.f,0.f,0.f}};

  for (int kt = 0; kt < ntile; kt++) {
    GLD16(Kn + (bh * S_ + kt * 64 + skey) * HD_ + schunk,      &Ks[0][0] + tid * 8);
    GLD16(Kn + (bh * S_ + kt * 64 + skey) * HD_ + 32 + schunk, &Ks[1][0] + tid * 8);
    GLD16(Vt + (bh * HD_ + skey) * S_ + kt * 64 + schunk,      &Vts[0][0] + tid * 8);
    GLD16(Vt + (bh * HD_ + skey) * S_ + kt * 64 + 32 + schunk, &Vts[1][0] + tid * 8);
    __syncthreads();

    f32x4 sacc[2][4] = {};
    for (int tn = 0; tn < 4; tn++) {
      f16x8 kf0 = *(const f16x8*)(&Ks[0][0] + (tn * 16 + l15) * 32 + qd * 8);
      f16x8 kf1 = *(const f16x8*)(&Ks[1][0] + (tn * 16 + l15) * 32 + qd * 8);
      for (int mt = 0; mt < 2; mt++) {
        sacc[mt][tn] = __builtin_amdgcn_mfma_f32_16x16x32_f16(qf[mt][0], kf0, sacc[mt][tn], 0, 0, 0);
        sacc[mt][tn] = __builtin_amdgcn_mfma_f32_16x16x32_f16(qf[mt][1], kf1, sacc[mt][tn], 0, 0, 0);
      }
    }

    for (int mt = 0; mt < 2; mt++)
      for (int tn = 0; tn < 4; tn++) {
        int kg = kt * 64 + tn * 16 + l15;
        for (int r = 0; r < 4; r++) {
          float p = (kg < len) ? __expf(sacc[mt][tn][r]) : 0.f;
          unsigned short pb = f2bf(p);
          den[mt][r] += bf2f(pb);
          Ps[wave][(mt * 16 + qd * 4 + r) * 72 + tn * 16 + l15] = pb;
        }
      }

    bf16x8 pf[2][2];
    for (int mt = 0; mt < 2; mt++) {
      pf[mt][0] = *(const bf16x8*)(&Ps[wave][(mt * 16 + l15) * 72 + qd * 8]);
      pf[mt][1] = *(const bf16x8*)(&Ps[wave][(mt * 16 + l15) * 72 + 32 + qd * 8]);
    }
    for (int t = 0; t < 4; t++) {
      bf16x8 vf0 = *(const bf16x8*)(&Vts[0][0] + (t * 16 + l15) * 32 + qd * 8);
      bf16x8 vf1 = *(const bf16x8*)(&Vts[1][0] + (t * 16 + l15) * 32 + qd * 8);
      for (int mt = 0; mt < 2; mt++) {
        o[mt][t] = __builtin_amdgcn_mfma_f32_16x16x32_bf16(pf[mt][0], vf0, o[mt][t], 0, 0, 0);
        o[mt][t] = __builtin_amdgcn_mfma_f32_16x16x32_bf16(pf[mt][1], vf1, o[mt][t], 0, 0, 0);
      }
    }
    __syncthreads();
  }

  for (int mt = 0; mt < 2; mt++)
    for (int t = 0; t < 4; t++)
      for (int r = 0; r < 4; r++) o[mt][t][r] += tv[t];

  float tden = (float)(S_ - len);
  for (int mt = 0; mt < 2; mt++)
    for (int r = 0; r < 4; r++) {
      for (int off = 1; off < 16; off <<= 1)
        den[mt][r] += __shfl_xor(den[mt][r], off, 64);
      den[mt][r] += tden;
    }

  for (int mt = 0; mt < 2; mt++)
    for (int t = 0; t < 4; t++)
      for (int r = 0; r < 4; r++) {
        long s = q0 + wave * 32 + mt * 16 + qd * 4 + r;
        long dcol = (long)h * HD_ + t * 16 + l15;
        out[((long)b * S_ + s) * D_ + dcol] = o[mt][t][r] / den[mt][r];
      }
}

// ----------------------------------------------------------------- launch ---
extern "C" void kernel_launch(void* const* d_in, const int* in_sizes, int n_in,
                              void* d_out, int out_size, void* d_ws, size_t ws_size,
                              hipStream_t stream) {
  const float* x     = (const float*)d_in[0];
  const int*  seq    = (const int*)d_in[1];
  const float* Wq    = (const float*)d_in[2];
  const float* bq    = (const float*)d_in[3];
  const float* Wk    = (const float*)d_in[4];
  const float* bk    = (const float*)d_in[5];
  const float* Wv    = (const float*)d_in[6];
  const float* bv    = (const float*)d_in[7];
  const float* ln_g  = (const float*)d_in[8];
  const float* ln_b  = (const float*)d_in[9];
  float* out = (float*)d_out;

  char* ws = (char*)d_ws;
  _Float16* xh  = (_Float16*)(ws);                          // 8 MB
  _Float16* wqh = (_Float16*)(ws + (8l  << 20));            // 2 MB
  _Float16* wkh = (_Float16*)(ws + (10l << 20));            // 2 MB
  _Float16* wvh = (_Float16*)(ws + (12l << 20));            // 2 MB
  float*    Vtail = (float*)(ws + (14l << 20));             // 16 KB
  _Float16* qh  = (_Float16*)(ws + (16l << 20));            // 8 MB
  _Float16* kh  = (_Float16*)(ws + (24l << 20));            // 8 MB
  _Float16* vh  = (_Float16*)(ws + (32l << 20));            // 8 MB
  _Float16* Qn  = (_Float16*)(ws + (40l << 20));            // 8 MB
  _Float16* Kn  = (_Float16*)(ws + (48l << 20));            // 8 MB
  unsigned short* Vt = (unsigned short*)(ws + (56l << 20)); // 8 MB

  cvt_all<<<7172, 256, 0, stream>>>(x, xh, Wq, wqh, Wk, wkh, Wv, wvh, Vtail);

  dim3 g1(D_ / 64, (B_ * S_) / 128, 1);
  gemm_bt_bias<<<g1, 256, 0, stream>>>(xh, wqh, bq, qh, wqh, bq, qh,
                                       B_ * S_, D_, D_);
  dim3 g2(D_ / 128, (B_ * S_) / 128, 2);
  gemm_bt_bias128<<<g2, 256, 0, stream>>>(qh, wkh, bk, kh, wvh, bv, vh,
                                          B_ * S_, D_, D_);

  dim3 g3(S_ / 64, H_, B_);
  ln_qkv<<<g3, 256, 0, stream>>>(qh, kh, vh, ln_g, ln_b, seq, Qn, Kn, Vt, Vtail);

  dim3 g4(B_, H_, S_ / 128);
  attn<<<g4, 256, 0, stream>>>(Qn, Kn, Vt, Vtail, seq, out);
}

// Round 12
// 180.555 us; speedup vs baseline: 1.1512x; 1.0462x over previous
//
#include <hip/hip_runtime.h>

#define B_  4
#define S_  1024
#define D_  1024
#define H_  16
#define HD_ 64
#define EPS_ 1e-5f

typedef _Float16 f16x8 __attribute__((ext_vector_type(8)));
typedef _Float16 f16x4 __attribute__((ext_vector_type(4)));
typedef __bf16 bf16x8 __attribute__((ext_vector_type(8)));
typedef float  f32x4  __attribute__((ext_vector_type(4)));
typedef unsigned short ushort8v __attribute__((ext_vector_type(8)));

static __device__ __forceinline__ unsigned short f2bf(float f) {
  union { float f; unsigned u; } v; v.f = f;
  unsigned r = v.u + 0x7fffu + ((v.u >> 16) & 1u);
  return (unsigned short)(r >> 16);
}
static __device__ __forceinline__ float bf2f(unsigned short u) {
  union { unsigned u; float f; } v; v.u = ((unsigned)u) << 16;
  return v.f;
}

// async global->LDS, 16B per lane; LDS dest is wave-uniform base + lane*16
#define GLD16(gp, lp) __builtin_amdgcn_global_load_lds( \
    (const __attribute__((address_space(1))) void*)(gp), \
    (__attribute__((address_space(3))) void*)(lp), 16, 0, 0)

// ---------------------------------------------------------------- convert ---
__global__ __launch_bounds__(256) void cvt_all(
    const float* __restrict__ x,  _Float16* __restrict__ xh,
    const float* __restrict__ Wq, _Float16* __restrict__ wqh,
    const float* __restrict__ Wk, _Float16* __restrict__ wkh,
    const float* __restrict__ Wv, _Float16* __restrict__ wvh,
    float* __restrict__ Vtail) {
  int bid = blockIdx.x;
  if (bid >= 7168) {                    // 4 blocks zero Vtail (B*H*HD f32)
    int i = (bid - 7168) * 1024 + threadIdx.x * 4;
    *(float4*)(Vtail + i) = make_float4(0.f, 0.f, 0.f, 0.f);
    return;
  }
  const float* src; _Float16* dst; int base;
  if (bid < 4096)      { src = x;  dst = xh;  base = bid; }
  else if (bid < 5120) { src = Wq; dst = wqh; base = bid - 4096; }
  else if (bid < 6144) { src = Wk; dst = wkh; base = bid - 5120; }
  else                 { src = Wv; dst = wvh; base = bid - 6144; }
  int i = base * 1024 + threadIdx.x * 4;
  float4 f = *(const float4*)(src + i);
  f16x4 h;
  h.x = (_Float16)f.x; h.y = (_Float16)f.y; h.z = (_Float16)f.z; h.w = (_Float16)f.w;
  *(f16x4*)(dst + i) = h;
}

// ---------------------------------------------- GEMM 128x64, BK=64 (gemm1) ---
// R9-VERIFIED verbatim.
__global__ __launch_bounds__(256, 2) void gemm_bt_bias(
    const _Float16* __restrict__ A,
    const _Float16* __restrict__ B0, const float* __restrict__ bias0,
    _Float16* __restrict__ C0,
    const _Float16* __restrict__ B1, const float* __restrict__ bias1,
    _Float16* __restrict__ C1,
    int M, int N, int K)
{
  const _Float16* Bm = blockIdx.z ? B1 : B0;
  const float* bias  = blockIdx.z ? bias1 : bias0;
  _Float16* C        = blockIdx.z ? C1 : C0;

  __shared__ _Float16 As[2 * 128 * 32];   // 16 KB
  __shared__ _Float16 Bs[2 * 64 * 32];    //  8 KB

  int tid  = threadIdx.x;
  int lane = tid & 63;
  int wave = tid >> 6;
  int wm = wave >> 1, wn = wave & 1;
  int qd = lane >> 4, l15 = lane & 15;

  long row0 = (long)blockIdx.y * 128;
  long col0 = (long)blockIdx.x * 64;

  int r_a = tid >> 2;
  int c_a = (tid & 3) * 8;

  f32x4 acc[4][2] = {};

  for (int kk = 0; kk < K; kk += 64) {
    GLD16(A  + (row0 + r_a) * K + kk + c_a,           As + tid * 8);
    GLD16(A  + (row0 + 64 + r_a) * K + kk + c_a,      As + 2048 + tid * 8);
    GLD16(A  + (row0 + r_a) * K + kk + 32 + c_a,      As + 4096 + tid * 8);
    GLD16(A  + (row0 + 64 + r_a) * K + kk + 32 + c_a, As + 6144 + tid * 8);
    GLD16(Bm + (col0 + r_a) * K + kk + c_a,           Bs + tid * 8);
    GLD16(Bm + (col0 + r_a) * K + kk + 32 + c_a,      Bs + 2048 + tid * 8);
    __syncthreads();

    for (int ks = 0; ks < 2; ks++) {
      f16x8 af[4], bfr[2];
      for (int t = 0; t < 4; t++)
        af[t]  = *(const f16x8*)(As + ks * 4096 + (wm * 64 + t * 16 + l15) * 32 + qd * 8);
      for (int j = 0; j < 2; j++)
        bfr[j] = *(const f16x8*)(Bs + ks * 2048 + (wn * 32 + j * 16 + l15) * 32 + qd * 8);
      for (int i = 0; i < 4; i++)
        for (int j = 0; j < 2; j++)
          acc[i][j] = __builtin_amdgcn_mfma_f32_16x16x32_f16(af[i], bfr[j], acc[i][j], 0, 0, 0);
    }
    __syncthreads();
  }

  for (int i = 0; i < 4; i++) {
    long row = row0 + wm * 64 + i * 16 + qd * 4;
    for (int j = 0; j < 2; j++) {
      long col = col0 + wn * 32 + j * 16 + l15;
      float bv = bias[col];
      for (int r = 0; r < 4; r++)
        C[(row + r) * N + col] = (_Float16)(acc[i][j][r] + bv);
    }
  }
}

// --------------------------------------------- GEMM 128x128, BK=64 (gemm2) ---
// R9-VERIFIED verbatim.
__global__ __launch_bounds__(256, 2) void gemm_bt_bias128(
    const _Float16* __restrict__ A,
    const _Float16* __restrict__ B0, const float* __restrict__ bias0,
    _Float16* __restrict__ C0,
    const _Float16* __restrict__ B1, const float* __restrict__ bias1,
    _Float16* __restrict__ C1,
    int M, int N, int K)
{
  const _Float16* Bm = blockIdx.z ? B1 : B0;
  const float* bias  = blockIdx.z ? bias1 : bias0;
  _Float16* C        = blockIdx.z ? C1 : C0;

  __shared__ _Float16 As[2 * 128 * 32];   // 16 KB
  __shared__ _Float16 Bs[2 * 128 * 32];   // 16 KB

  int tid  = threadIdx.x;
  int lane = tid & 63;
  int wave = tid >> 6;
  int wm = wave >> 1, wn = wave & 1;
  int qd = lane >> 4, l15 = lane & 15;

  long row0 = (long)blockIdx.y * 128;
  long col0 = (long)blockIdx.x * 128;

  int r_a = tid >> 2;
  int c_a = (tid & 3) * 8;

  f32x4 acc[4][4] = {};

  for (int kk = 0; kk < K; kk += 64) {
    GLD16(A  + (row0 + r_a) * K + kk + c_a,           As + tid * 8);
    GLD16(A  + (row0 + 64 + r_a) * K + kk + c_a,      As + 2048 + tid * 8);
    GLD16(A  + (row0 + r_a) * K + kk + 32 + c_a,      As + 4096 + tid * 8);
    GLD16(A  + (row0 + 64 + r_a) * K + kk + 32 + c_a, As + 6144 + tid * 8);
    GLD16(Bm + (col0 + r_a) * K + kk + c_a,           Bs + tid * 8);
    GLD16(Bm + (col0 + 64 + r_a) * K + kk + c_a,      Bs + 2048 + tid * 8);
    GLD16(Bm + (col0 + r_a) * K + kk + 32 + c_a,      Bs + 4096 + tid * 8);
    GLD16(Bm + (col0 + 64 + r_a) * K + kk + 32 + c_a, Bs + 6144 + tid * 8);
    __syncthreads();

    for (int ks = 0; ks < 2; ks++) {
      f16x8 af[4], bfr[4];
      for (int t = 0; t < 4; t++) {
        af[t]  = *(const f16x8*)(As + ks * 4096 + (wm * 64 + t * 16 + l15) * 32 + qd * 8);
        bfr[t] = *(const f16x8*)(Bs + ks * 4096 + (wn * 64 + t * 16 + l15) * 32 + qd * 8);
      }
      for (int i = 0; i < 4; i++)
        for (int j = 0; j < 4; j++)
          acc[i][j] = __builtin_amdgcn_mfma_f32_16x16x32_f16(af[i], bfr[j], acc[i][j], 0, 0, 0);
    }
    __syncthreads();
  }

  for (int i = 0; i < 4; i++) {
    long row = row0 + wm * 64 + i * 16 + qd * 4;
    for (int j = 0; j < 4; j++) {
      long col = col0 + wn * 64 + j * 16 + l15;
      float bv = bias[col];
      for (int r = 0; r < 4; r++)
        C[(row + r) * N + col] = (_Float16)(acc[i][j][r] + bv);
    }
  }
}

// ----------------------------------------------------------------- LN qkv ---
// R5-VERIFIED body with ONE change: all 24 loads (q,k,v x 8) issued up-front
// into registers before any compute. The old body serialized three latency
// epochs (load q -> wait -> compute -> load k -> ...) at 4 waves/CU, giving
// the measured 46.6 us @ 1.67 TB/s (latency-bound). 24 outstanding loads
// per thread triples in-flight bytes. ~120 VGPR, no bounds cap (grid is
// 256 blocks = 1 block/CU; occupancy bound is the grid, not registers).
__global__ __launch_bounds__(256) void ln_qkv(
    const _Float16* __restrict__ qh,
    const _Float16* __restrict__ kh,
    const _Float16* __restrict__ vh,
    const float* __restrict__ ln_g, const float* __restrict__ ln_b,
    const int* __restrict__ seq_len,
    _Float16* __restrict__ Qn,
    _Float16* __restrict__ Kn,
    unsigned short* __restrict__ Vt,
    float* __restrict__ Vtail)
{
  __shared__ unsigned short Vls[256][68];   // bf16, padded ~34 KB
  int tid = threadIdx.x;
  int s0 = blockIdx.x * 256;
  int h = blockIdx.y, b = blockIdx.z;
  long bh = (long)b * H_ + h;
  long s = s0 + tid;
  long inbase  = ((long)b * S_ + s) * D_ + (long)h * HD_;
  long outbase = (bh * S_ + s) * HD_;

  // ---- prefetch ALL of q,k,v for this row (24 x 16B loads in flight) ----
  f16x8 rq[8], rk[8], rv[8];
  for (int i = 0; i < 8; i++) {
    rq[i] = *(const f16x8*)(qh + inbase + i * 8);
    rk[i] = *(const f16x8*)(kh + inbase + i * 8);
    rv[i] = *(const f16x8*)(vh + inbase + i * 8);
  }

  // ---- q ----
  {
    float sum = 0.f, sq = 0.f;
    for (int i = 0; i < 8; i++)
      for (int j = 0; j < 8; j++) { float xv = (float)rq[i][j]; sum += xv; sq = fmaf(xv, xv, sq); }
    float m = sum * (1.f / 64.f);
    float inv = rsqrtf(sq * (1.f / 64.f) - m * m + EPS_);
    for (int i = 0; i < 8; i++) {
      f16x8 o;
      for (int j = 0; j < 8; j++)
        o[j] = (_Float16)(((float)rq[i][j] - m) * inv * ln_g[i * 8 + j] + ln_b[i * 8 + j]);
      *(f16x8*)(Qn + outbase + i * 8) = o;
    }
  }
  // ---- k ----
  {
    float sum = 0.f, sq = 0.f;
    for (int i = 0; i < 8; i++)
      for (int j = 0; j < 8; j++) { float xv = (float)rk[i][j]; sum += xv; sq = fmaf(xv, xv, sq); }
    float m = sum * (1.f / 64.f);
    float inv = rsqrtf(sq * (1.f / 64.f) - m * m + EPS_);
    for (int i = 0; i < 8; i++) {
      f16x8 o;
      for (int j = 0; j < 8; j++)
        o[j] = (_Float16)(((float)rk[i][j] - m) * inv * ln_g[i * 8 + j] + ln_b[i * 8 + j]);
      *(f16x8*)(Kn + outbase + i * 8) = o;
    }
  }
  // ---- v (normalize to bf16 into LDS, then transposed write-out) ----
  {
    float sum = 0.f, sq = 0.f;
    for (int i = 0; i < 8; i++)
      for (int j = 0; j < 8; j++) { float xv = (float)rv[i][j]; sum += xv; sq = fmaf(xv, xv, sq); }
    float m = sum * (1.f / 64.f);
    float inv = rsqrtf(sq * (1.f / 64.f) - m * m + EPS_);
    for (int i = 0; i < 8; i++)
      for (int j = 0; j < 8; j++)
        Vls[tid][i * 8 + j] = f2bf(((float)rv[i][j] - m) * inv * ln_g[i * 8 + j] + ln_b[i * 8 + j]);
  }
  __syncthreads();
  int d = tid >> 2, sc = tid & 3;
  int len = seq_len[b];
  long vbase = (bh * HD_ + d) * S_ + s0 + sc * 64;
  float tsum = 0.f;
  for (int j0 = 0; j0 < 64; j0 += 8) {
    ushort8v w;
    for (int jj = 0; jj < 8; jj++) {
      unsigned short ub = Vls[sc * 64 + j0 + jj][d];
      w[jj] = ub;
      if (s0 + sc * 64 + j0 + jj >= len) tsum += bf2f(ub);
    }
    *(ushort8v*)(Vt + vbase + j0) = w;
  }
  if (s0 + sc * 64 + 64 > len)            // any tail rows in this chunk
    atomicAdd(&Vtail[bh * HD_ + d], tsum);
}

// -------------------------------------------------------------- attention ---
// R9-VERIFIED verbatim.
__global__ __launch_bounds__(256, 2) void attn(
    const _Float16* __restrict__ Qn,
    const _Float16* __restrict__ Kn,
    const unsigned short* __restrict__ Vt,
    const float* __restrict__ Vtail,
    const int* __restrict__ seq_len,
    float* __restrict__ out)
{
  __shared__ _Float16 Ks[2][64 * 32];        // [d-half][key][32]    8 KB
  __shared__ unsigned short Vts[2][64 * 32]; // [key-half][d][32]    8 KB
  __shared__ unsigned short Ps[4][32 * 72];  // per-wave P [32m][72] 18 KB

  int tid = threadIdx.x, lane = tid & 63, wave = tid >> 6;
  int qd = lane >> 4, l15 = lane & 15;
  int b = blockIdx.x;                        // b fastest: len load-balance
  int h = blockIdx.y;
  int q0 = blockIdx.z * 128;
  long bh = (long)b * H_ + h;
  int len = seq_len[b];
  int ntile = (len + 63) >> 6;               // tiles containing any key < len

  int skey = tid >> 2;
  int schunk = (tid & 3) * 8;

  f16x8 qf[2][2];
  for (int mt = 0; mt < 2; mt++) {
    const _Float16* qp = Qn + (bh * S_ + q0 + wave * 32 + mt * 16 + l15) * HD_;
    qf[mt][0] = *(const f16x8*)(qp + qd * 8);
    qf[mt][1] = *(const f16x8*)(qp + 32 + qd * 8);
  }
  float tv[4];
  for (int t = 0; t < 4; t++) tv[t] = Vtail[bh * HD_ + t * 16 + l15];

  f32x4 o[2][4] = {};
  float den[2][4] = {{0.f,0.f,0.f,0.f},{0.f,0.f,0.f,0.f}};

  for (int kt = 0; kt < ntile; kt++) {
    GLD16(Kn + (bh * S_ + kt * 64 + skey) * HD_ + schunk,      &Ks[0][0] + tid * 8);
    GLD16(Kn + (bh * S_ + kt * 64 + skey) * HD_ + 32 + schunk, &Ks[1][0] + tid * 8);
    GLD16(Vt + (bh * HD_ + skey) * S_ + kt * 64 + schunk,      &Vts[0][0] + tid * 8);
    GLD16(Vt + (bh * HD_ + skey) * S_ + kt * 64 + 32 + schunk, &Vts[1][0] + tid * 8);
    __syncthreads();

    f32x4 sacc[2][4] = {};
    for (int tn = 0; tn < 4; tn++) {
      f16x8 kf0 = *(const f16x8*)(&Ks[0][0] + (tn * 16 + l15) * 32 + qd * 8);
      f16x8 kf1 = *(const f16x8*)(&Ks[1][0] + (tn * 16 + l15) * 32 + qd * 8);
      for (int mt = 0; mt < 2; mt++) {
        sacc[mt][tn] = __builtin_amdgcn_mfma_f32_16x16x32_f16(qf[mt][0], kf0, sacc[mt][tn], 0, 0, 0);
        sacc[mt][tn] = __builtin_amdgcn_mfma_f32_16x16x32_f16(qf[mt][1], kf1, sacc[mt][tn], 0, 0, 0);
      }
    }

    for (int mt = 0; mt < 2; mt++)
      for (int tn = 0; tn < 4; tn++) {
        int kg = kt * 64 + tn * 16 + l15;
        for (int r = 0; r < 4; r++) {
          float p = (kg < len) ? __expf(sacc[mt][tn][r]) : 0.f;
          unsigned short pb = f2bf(p);
          den[mt][r] += bf2f(pb);
          Ps[wave][(mt * 16 + qd * 4 + r) * 72 + tn * 16 + l15] = pb;
        }
      }

    bf16x8 pf[2][2];
    for (int mt = 0; mt < 2; mt++) {
      pf[mt][0] = *(const bf16x8*)(&Ps[wave][(mt * 16 + l15) * 72 + qd * 8]);
      pf[mt][1] = *(const bf16x8*)(&Ps[wave][(mt * 16 + l15) * 72 + 32 + qd * 8]);
    }
    for (int t = 0; t < 4; t++) {
      bf16x8 vf0 = *(const bf16x8*)(&Vts[0][0] + (t * 16 + l15) * 32 + qd * 8);
      bf16x8 vf1 = *(const bf16x8*)(&Vts[1][0] + (t * 16 + l15) * 32 + qd * 8);
      for (int mt = 0; mt < 2; mt++) {
        o[mt][t] = __builtin_amdgcn_mfma_f32_16x16x32_bf16(pf[mt][0], vf0, o[mt][t], 0, 0, 0);
        o[mt][t] = __builtin_amdgcn_mfma_f32_16x16x32_bf16(pf[mt][1], vf1, o[mt][t], 0, 0, 0);
      }
    }
    __syncthreads();
  }

  for (int mt = 0; mt < 2; mt++)
    for (int t = 0; t < 4; t++)
      for (int r = 0; r < 4; r++) o[mt][t][r] += tv[t];

  float tden = (float)(S_ - len);
  for (int mt = 0; mt < 2; mt++)
    for (int r = 0; r < 4; r++) {
      for (int off = 1; off < 16; off <<= 1)
        den[mt][r] += __shfl_xor(den[mt][r], off, 64);
      den[mt][r] += tden;
    }

  for (int mt = 0; mt < 2; mt++)
    for (int t = 0; t < 4; t++)
      for (int r = 0; r < 4; r++) {
        long s = q0 + wave * 32 + mt * 16 + qd * 4 + r;
        long dcol = (long)h * HD_ + t * 16 + l15;
        out[((long)b * S_ + s) * D_ + dcol] = o[mt][t][r] / den[mt][r];
      }
}

// ----------------------------------------------------------------- launch ---
extern "C" void kernel_launch(void* const* d_in, const int* in_sizes, int n_in,
                              void* d_out, int out_size, void* d_ws, size_t ws_size,
                              hipStream_t stream) {
  const float* x     = (const float*)d_in[0];
  const int*  seq    = (const int*)d_in[1];
  const float* Wq    = (const float*)d_in[2];
  const float* bq    = (const float*)d_in[3];
  const float* Wk    = (const float*)d_in[4];
  const float* bk    = (const float*)d_in[5];
  const float* Wv    = (const float*)d_in[6];
  const float* bv    = (const float*)d_in[7];
  const float* ln_g  = (const float*)d_in[8];
  const float* ln_b  = (const float*)d_in[9];
  float* out = (float*)d_out;

  char* ws = (char*)d_ws;
  _Float16* xh  = (_Float16*)(ws);                          // 8 MB
  _Float16* wqh = (_Float16*)(ws + (8l  << 20));            // 2 MB
  _Float16* wkh = (_Float16*)(ws + (10l << 20));            // 2 MB
  _Float16* wvh = (_Float16*)(ws + (12l << 20));            // 2 MB
  float*    Vtail = (float*)(ws + (14l << 20));             // 16 KB
  _Float16* qh  = (_Float16*)(ws + (16l << 20));            // 8 MB
  _Float16* kh  = (_Float16*)(ws + (24l << 20));            // 8 MB
  _Float16* vh  = (_Float16*)(ws + (32l << 20));            // 8 MB
  _Float16* Qn  = (_Float16*)(ws + (40l << 20));            // 8 MB
  _Float16* Kn  = (_Float16*)(ws + (48l << 20));            // 8 MB
  unsigned short* Vt = (unsigned short*)(ws + (56l << 20)); // 8 MB

  cvt_all<<<7172, 256, 0, stream>>>(x, xh, Wq, wqh, Wk, wkh, Wv, wvh, Vtail);

  dim3 g1(D_ / 64, (B_ * S_) / 128, 1);
  gemm_bt_bias<<<g1, 256, 0, stream>>>(xh, wqh, bq, qh, wqh, bq, qh,
                                       B_ * S_, D_, D_);
  dim3 g2(D_ / 128, (B_ * S_) / 128, 2);
  gemm_bt_bias128<<<g2, 256, 0, stream>>>(qh, wkh, bk, kh, wvh, bv, vh,
                                          B_ * S_, D_, D_);

  dim3 g3(S_ / 256, H_, B_);
  ln_qkv<<<g3, 256, 0, stream>>>(qh, kh, vh, ln_g, ln_b, seq, Qn, Kn, Vt, Vtail);

  dim3 g4(B_, H_, S_ / 128);
  attn<<<g4, 256, 0, stream>>>(Qn, Kn, Vt, Vtail, seq, out);
}